// Round 3
// baseline (500.743 us; speedup 1.0000x reference)
//
#include <hip/hip_runtime.h>
#include <cfloat>
#include <climits>

#define NEG 0.2f
#define GEPS 1e-5f
#define D 6
#define H 13   // 2*D+1
#define KOUT 16

#define M_CAND 8000   // candidate count (atoms) for both KNNs
#define NSL 8         // candidate slices per block (4 waves x 2 half-waves)
#define SLICE 1000    // M_CAND / NSL
#define NCH 4         // chunks per slice
#define CHUNK 250     // SLICE / NCH
#define QB 32         // queries per block
#define SW 20         // survivor slots per (query, slice)
#define MARGIN 0.05f

__device__ __forceinline__ float lrelu(float x){ return x >= 0.f ? x : NEG*x; }

// pack xyz (n,3) -> float4 {x,y,z,|p|^2} (contract-off to match reference sums)
__global__ void pack_kernel(const float* __restrict__ xyz, float4* __restrict__ out, int n){
  int i = blockIdx.x*blockDim.x + threadIdx.x;
  if (i >= n) return;
  float x = xyz[3*i], y = xyz[3*i+1], z = xyz[3*i+2];
  float sq;
  {
#pragma clang fp contract(off)
    sq = (x*x + y*y) + z*z;
  }
  out[i] = make_float4(x,y,z,sq);
}

// atomtypes (n,6) -> 2-layer MLP -> out (n,6)
__global__ void tt_kernel(const float* __restrict__ at_in,
                          const float* __restrict__ w1, const float* __restrict__ b1,
                          const float* __restrict__ w2, const float* __restrict__ b2,
                          float* __restrict__ out, int n){
  int i = blockIdx.x*blockDim.x + threadIdx.x;
  if (i >= n) return;
  float x[D], h[D];
  #pragma unroll
  for (int j=0;j<D;j++) x[j] = at_in[i*D+j];
  #pragma unroll
  for (int o=0;o<D;o++){
    float acc = b1[o];
    #pragma unroll
    for (int j=0;j<D;j++) acc += w1[o*D+j]*x[j];
    h[o] = lrelu(acc);
  }
  #pragma unroll
  for (int o=0;o<D;o++){
    float acc = b2[o];
    #pragma unroll
    for (int j=0;j<D;j++) acc += w2[o*D+j]*h[j];
    out[i*D+o] = acc;
  }
}

// ascending lexicographic (d, i) bitonic sort across 64 lanes
__device__ __forceinline__ void sort64pair(float& d, int& i, int lane){
  #pragma unroll
  for (int k = 2; k <= 64; k <<= 1){
    #pragma unroll
    for (int j = k >> 1; j >= 1; j >>= 1){
      float od = __shfl_xor(d, j);
      int   oi = __shfl_xor(i, j);
      bool lower = (lane & j) == 0;
      bool asc   = (lane & k) == 0;
      bool oless = (od < d) || (od == d && oi < i);
      bool take  = (lower == asc) ? oless : !oless;
      d = take ? od : d;
      i = take ? oi : i;
    }
  }
}

// Lane-per-query KNN: block = 256 threads = 4 waves; block owns QB=32 queries.
// Lane l: query = l&31, half h = l>>5; slice s = wave*2+h scans cands
// [s*SLICE, (s+1)*SLICE). Phase 1: per-lane chunk-mins of e = |c|^2 - 2 q.c
// (fma space). Threshold T = KSEL-th smallest of the 32 chunk-mins (+MARGIN)
// is a provable upper bound on the true KSEL-th neighbor. Phase 2: collect
// survivor indices per (q, slice). Phase 3: exact-distance re-sort (reference
// formula, contract-off) of survivors across lanes, emit KOUT from OUT_OFF.
template<int KSEL, int OUT_OFF>
__global__ __launch_bounds__(256)
void knn2_kernel(const float4* __restrict__ cand,
                 const float4* __restrict__ qarr, int nq,
                 int* __restrict__ oidx, float* __restrict__ odist){
  __shared__ float cm[QB][NSL*NCH + 1];     // chunk minima, padded row
  __shared__ int   slots[QB][NSL][SW];      // survivor indices
  __shared__ int   cnts[QB][NSL];
  __shared__ int   ovfq[QB];

  const int tid  = threadIdx.x;
  const int w    = __builtin_amdgcn_readfirstlane(tid >> 6);
  const int lane = tid & 63;
  const int ql   = lane & (QB-1);
  const int hh   = lane >> 5;
  const int s    = w*2 + hh;
  int qg = blockIdx.x*QB + ql;
  if (qg >= nq) qg = nq - 1;              // duplicate-compute guard (benign)
  const float4 qp = qarr[qg];

  if (tid < QB) ovfq[tid] = 0;

  const float4* __restrict__ base = cand + s*SLICE;

  // ---- phase 1: chunk minima of e = cw - 2*dot (fma space) ----
  float m[NCH];
  #pragma unroll
  for (int c=0;c<NCH;c++) m[c] = FLT_MAX;
  #pragma unroll
  for (int c=0;c<NCH;c++){
    #pragma unroll 4
    for (int i=0;i<CHUNK;i++){
      float4 cp = base[c*CHUNK + i];
      float dot = qp.x*cp.x + qp.y*cp.y + qp.z*cp.z;
      float e = fmaf(-2.f, dot, cp.w);
      m[c] = fminf(m[c], e);
    }
  }
  #pragma unroll
  for (int c=0;c<NCH;c++) cm[ql][s*NCH + c] = m[c];
  __syncthreads();

  // ---- phase 1b: per-lane threshold = KSEL-th smallest of 32 chunk-mins ----
  float v[NSL*NCH];
  #pragma unroll
  for (int i=0;i<NSL*NCH;i++) v[i] = cm[ql][i];
  #pragma unroll
  for (int k=2;k<=32;k<<=1){
    #pragma unroll
    for (int j=k>>1;j>=1;j>>=1){
      #pragma unroll
      for (int i=0;i<32;i++){
        int l2 = i ^ j;
        if (l2 > i){
          bool up = (i & k) == 0;
          float a=v[i], b=v[l2];
          if ((a > b) == up){ v[i]=b; v[l2]=a; }
        }
      }
    }
  }
  const float T = v[KSEL-1] + MARGIN;

  // ---- phase 2: collect survivor indices for (ql, s) ----
  int cnt = 0;
  #pragma unroll 4
  for (int i=0;i<SLICE;i++){
    float4 cp = base[i];
    float dot = qp.x*cp.x + qp.y*cp.y + qp.z*cp.z;
    float e = fmaf(-2.f, dot, cp.w);
    if (e <= T){
      if (cnt < SW) slots[ql][s][cnt] = s*SLICE + i;
      cnt++;
    }
  }
  if (cnt > SW){ ovfq[ql] = 1; cnt = SW; }
  cnts[ql][s] = cnt;
  __syncthreads();

  // ---- phase 3: per-query exact select (wave w handles 8 queries) ----
  for (int qi = 0; qi < QB/4; ++qi){
    const int qq = w*(QB/4) + qi;
    const int qgq0 = blockIdx.x*QB + qq;
    if (qgq0 >= nq) continue;            // wave-uniform
    const int qgq = qgq0;
    int cu[NSL];
    #pragma unroll
    for (int u=0;u<NSL;u++) cu[u] = cnts[qq][u];
    int Ctot = 0;
    #pragma unroll
    for (int u=0;u<NSL;u++) Ctot += cu[u];
    const float qx=__shfl(qp.x,qq), qy=__shfl(qp.y,qq),
                qz=__shfl(qp.z,qq), qw=__shfl(qp.w,qq);

    if (ovfq[qq] == 0 && Ctot <= 64){
      // lane -> (slice, local offset)
      int rem = lane, sel = -1, loc = 0;
      #pragma unroll
      for (int u=0;u<NSL;u++){
        bool here = (sel < 0) && (rem < cu[u]);
        if (here){ sel = u; loc = rem; }
        if (sel < 0) rem -= cu[u];
      }
      int jv = INT_MAX; float d2 = FLT_MAX;
      if (sel >= 0){
        jv = slots[qq][sel][loc];
        float4 cp = cand[jv];
        {
#pragma clang fp contract(off)
          float dot = qx*cp.x + qy*cp.y + qz*cp.z;
          d2 = (qw + cp.w) - 2.0f*dot;
        }
      }
      sort64pair(d2, jv, lane);
      if (lane >= OUT_OFF && lane < OUT_OFF + KOUT){
        float4 cp = cand[jv];
        float dist;
        {
#pragma clang fp contract(off)
          float dx=qx-cp.x, dy=qy-cp.y, dz=qz-cp.z;
          dist = (dx*dx + dy*dy) + dz*dz;
        }
        oidx[(size_t)qgq*KOUT + (lane-OUT_OFF)] = jv;
        odist[(size_t)qgq*KOUT + (lane-OUT_OFF)] = dist;
      }
    } else {
      // rare fallback: serial exact top-KSEL on lane 0
      if (lane == 0){
        float bd[KSEL]; int bi[KSEL];
        #pragma unroll
        for (int t=0;t<KSEL;t++){ bd[t]=FLT_MAX; bi[t]=INT_MAX; }
        float cmd = FLT_MAX; int cmi = INT_MAX;
        const bool full = (ovfq[qq] != 0);
        const int nit = full ? M_CAND : NSL*SW;
        for (int e0 = 0; e0 < nit; ++e0){
          int j;
          if (full) j = e0;
          else {
            int u = e0 / SW, o = e0 % SW;
            if (o >= cu[u]) continue;
            j = slots[qq][u][o];
          }
          float4 cp = cand[j];
          float d2;
          {
#pragma clang fp contract(off)
            float dot = qx*cp.x + qy*cp.y + qz*cp.z;
            d2 = (qw + cp.w) - 2.0f*dot;
          }
          if (d2 < cmd || (d2 == cmd && j < cmi)){
            int rt = 0; float rmd=-FLT_MAX; int rmi=-1;
            for (int t=0;t<KSEL;t++){
              if (bd[t] > rmd || (bd[t]==rmd && bi[t]>rmi)){ rmd=bd[t]; rmi=bi[t]; rt=t; }
            }
            bd[rt]=d2; bi[rt]=j;
            cmd=-FLT_MAX; cmi=-1;
            for (int t=0;t<KSEL;t++){
              if (bd[t] > cmd || (bd[t]==cmd && bi[t]>cmi)){ cmd=bd[t]; cmi=bi[t]; }
            }
          }
        }
        for (int t=0;t<KSEL;t++){
          int rt=-1; float mnd=FLT_MAX; int mni=INT_MAX;
          for (int u2=0;u2<KSEL;u2++){
            if (bd[u2] < mnd || (bd[u2]==mnd && bi[u2]<mni)){ mnd=bd[u2]; mni=bi[u2]; rt=u2; }
          }
          bd[rt]=FLT_MAX; bi[rt]=INT_MAX;
          if (t >= OUT_OFF){
            float4 cp = cand[mni];
            float dist;
            {
#pragma clang fp contract(off)
              float dx=qx-cp.x, dy=qy-cp.y, dz=qz-cp.z;
              dist = (dx*dx + dy*dy) + dz*dz;
            }
            oidx[(size_t)qgq*KOUT + (t-OUT_OFF)] = mni;
            odist[(size_t)qgq*KOUT + (t-OUT_OFF)] = dist;
          }
        }
      }
    }
  }
}

// One message-passing block: out = self + lrelu(groupnorm(sum_k MLP(feat_k)))
// 4 threads per point: each handles 4 of the 16 neighbors, shfl-reduce.
template<bool SELF_ONES>
__global__ __launch_bounds__(256)
void mp_kernel(const float* __restrict__ self_feat,
               const float* __restrict__ nb_src,
               const int* __restrict__ idx,
               const float* __restrict__ dists,
               const float* __restrict__ w1g, const float* __restrict__ b1g,
               const float* __restrict__ w2g, const float* __restrict__ b2g,
               const float* __restrict__ gam, const float* __restrict__ bet,
               float* __restrict__ out, int n){
  __shared__ float w1[H*H], b1v[H], w2[D*H], b2v[D], gm[D], bt[D];
  for (int t=threadIdx.x; t<H*H; t+=blockDim.x) w1[t]=w1g[t];
  if (threadIdx.x < H) b1v[threadIdx.x]=b1g[threadIdx.x];
  for (int t=threadIdx.x; t<D*H; t+=blockDim.x) w2[t]=w2g[t];
  if (threadIdx.x < D){
    b2v[threadIdx.x]=b2g[threadIdx.x];
    gm[threadIdx.x]=gam[threadIdx.x];
    bt[threadIdx.x]=bet[threadIdx.x];
  }
  __syncthreads();
  int tt = blockIdx.x*blockDim.x + threadIdx.x;
  int p = tt >> 2, sub = tt & 3;
  if (p >= n) return;

  float s[D];
  #pragma unroll
  for (int j=0;j<D;j++) s[j] = SELF_ONES ? 1.0f : self_feat[p*D+j];
  float msg[D] = {0,0,0,0,0,0};

  #pragma unroll
  for (int u=0;u<KOUT/4;u++){
    int k = u*4 + sub;
    int j = idx[p*KOUT+k];
    float dd = dists[p*KOUT+k];
    float f[H];
    #pragma unroll
    for (int c=0;c<D;c++) f[c]=s[c];
    #pragma unroll
    for (int c=0;c<D;c++) f[D+c]=nb_src[j*D+c];
    f[2*D]=dd;
    float h[H];
    #pragma unroll
    for (int o=0;o<H;o++){
      float acc=b1v[o];
      #pragma unroll
      for (int c=0;c<H;c++) acc += w1[o*H+c]*f[c];
      h[o]=lrelu(acc);
    }
    #pragma unroll
    for (int o=0;o<D;o++){
      float acc=b2v[o];
      #pragma unroll
      for (int c=0;c<H;c++) acc += w2[o*H+c]*h[c];
      msg[o]+=acc;
    }
  }

  #pragma unroll
  for (int c=0;c<D;c++){
    msg[c] += __shfl_xor(msg[c], 1);
    msg[c] += __shfl_xor(msg[c], 2);
  }

  if (sub == 0){
    float y[D];
    #pragma unroll
    for (int gi=0; gi<2; gi++){
      float m0=msg[gi*3+0], m1=msg[gi*3+1], m2=msg[gi*3+2];
      float mu = ((m0+m1)+m2) / 3.0f;
      float d0=m0-mu, d1=m1-mu, d2v=m2-mu;
      float var = ((d0*d0 + d1*d1) + d2v*d2v) / 3.0f;
      float inv = 1.0f / sqrtf(var + GEPS);
      y[gi*3+0] = d0*inv;
      y[gi*3+1] = d1*inv;
      y[gi*3+2] = d2v*inv;
    }
    #pragma unroll
    for (int c=0;c<D;c++){
      float vv = y[c]*gm[c] + bt[c];
      out[p*D+c] = s[c] + lrelu(vv);
    }
  }
}

extern "C" void kernel_launch(void* const* d_in, const int* in_sizes, int n_in,
                              void* d_out, int out_size, void* d_ws, size_t ws_size,
                              hipStream_t stream){
  const float* xyz       = (const float*)d_in[0];
  const float* atom_xyz  = (const float*)d_in[1];
  const float* atomtypes = (const float*)d_in[2];
  const float* tt_w1 = (const float*)d_in[5];
  const float* tt_b1 = (const float*)d_in[6];
  const float* tt_w2 = (const float*)d_in[7];
  const float* tt_b2 = (const float*)d_in[8];
  const float* aa_w1 = (const float*)d_in[9];
  const float* aa_b1 = (const float*)d_in[10];
  const float* aa_w2 = (const float*)d_in[11];
  const float* aa_b2 = (const float*)d_in[12];
  const float* aa_gamma = (const float*)d_in[13];
  const float* aa_beta  = (const float*)d_in[14];
  const float* em_w1 = (const float*)d_in[15];
  const float* em_b1 = (const float*)d_in[16];
  const float* em_w2 = (const float*)d_in[17];
  const float* em_b2 = (const float*)d_in[18];
  const float* em_gamma = (const float*)d_in[19];
  const float* em_beta  = (const float*)d_in[20];

  const int n_pts = in_sizes[0]/3;
  const int n_at  = in_sizes[1]/3;

  char* ws = (char*)d_ws;
  float4* atomsP = (float4*)ws; ws += (size_t)n_at*sizeof(float4);
  float4* ptsP   = (float4*)ws; ws += (size_t)n_pts*sizeof(float4);
  float* fa   = (float*)ws; ws += (size_t)n_at*D*4;
  float* fb   = (float*)ws; ws += (size_t)n_at*D*4;
  int*   idxA = (int*)ws;   ws += (size_t)n_at*KOUT*4;
  float* distA= (float*)ws; ws += (size_t)n_at*KOUT*4;
  int*   idxP = (int*)ws;   ws += (size_t)n_pts*KOUT*4;
  float* distP= (float*)ws; ws += (size_t)n_pts*KOUT*4;
  float* ea   = (float*)ws; ws += (size_t)n_pts*D*4;
  float* eb   = (float*)ws; ws += (size_t)n_pts*D*4;
  float* outf = (float*)d_out;

  pack_kernel<<<(n_at +255)/256,256,0,stream>>>(atom_xyz, atomsP, n_at);
  pack_kernel<<<(n_pts+255)/256,256,0,stream>>>(xyz, ptsP, n_pts);

  tt_kernel<<<(n_at+255)/256,256,0,stream>>>(atomtypes, tt_w1,tt_b1,tt_w2,tt_b2, fa, n_at);

  knn2_kernel<17,1><<<(n_at +QB-1)/QB,256,0,stream>>>(atomsP, atomsP, n_at,  idxA, distA);

  mp_kernel<false><<<(n_at*4+255)/256,256,0,stream>>>(fa, fa, idxA, distA,
      aa_w1+0*H*H, aa_b1+0*H, aa_w2+0*D*H, aa_b2+0*D, aa_gamma+0*D, aa_beta+0*D, fb, n_at);
  mp_kernel<false><<<(n_at*4+255)/256,256,0,stream>>>(fb, fb, idxA, distA,
      aa_w1+1*H*H, aa_b1+1*H, aa_w2+1*D*H, aa_b2+1*D, aa_gamma+1*D, aa_beta+1*D, fa, n_at);
  mp_kernel<false><<<(n_at*4+255)/256,256,0,stream>>>(fa, fa, idxA, distA,
      aa_w1+2*H*H, aa_b1+2*H, aa_w2+2*D*H, aa_b2+2*D, aa_gamma+2*D, aa_beta+2*D, fb, n_at);
  // final atom features in fb

  knn2_kernel<16,0><<<(n_pts+QB-1)/QB,256,0,stream>>>(atomsP, ptsP, n_pts, idxP, distP);

  mp_kernel<true ><<<(n_pts*4+255)/256,256,0,stream>>>(nullptr, fb, idxP, distP,
      em_w1+0*H*H, em_b1+0*H, em_w2+0*D*H, em_b2+0*D, em_gamma+0*D, em_beta+0*D, ea, n_pts);
  mp_kernel<false><<<(n_pts*4+255)/256,256,0,stream>>>(ea, fb, idxP, distP,
      em_w1+1*H*H, em_b1+1*H, em_w2+1*D*H, em_b2+1*D, em_gamma+1*D, em_beta+1*D, eb, n_pts);
  mp_kernel<false><<<(n_pts*4+255)/256,256,0,stream>>>(eb, fb, idxP, distP,
      em_w1+2*H*H, em_b1+2*H, em_w2+2*D*H, em_b2+2*D, em_gamma+2*D, em_beta+2*D, outf, n_pts);
}

// Round 4
// 393.883 us; speedup vs baseline: 1.2713x; 1.2713x over previous
//
#include <hip/hip_runtime.h>
#include <cfloat>
#include <climits>

#define NEG 0.2f
#define GEPS 1e-5f
#define D 6
#define H 13   // 2*D+1
#define KOUT 16

#define M_CAND 8000   // candidate count (atoms)
#define NRG 8         // candidate ranges (4 waves x 2 half-waves)
#define RNG 1000      // M_CAND / NRG
#define RPAD 1024     // padded range (8 chunks x 128)
#define NCH 8         // chunks per range
#define CHUNK 128     // padded chunk
#define QB 32         // queries per block
#define SW 24         // survivor slots per (query, range)
#define MARGIN 0.05f

__device__ __forceinline__ float lrelu(float x){ return x >= 0.f ? x : NEG*x; }

// fast-space score: e = |c|^2 - 2 q.c  (identical expression in pass1/pass2)
__device__ __forceinline__ float escore(const float4& q, const float4& c){
  float dot = fmaf(q.x, c.x, fmaf(q.y, c.y, q.z*c.z));
  return fmaf(-2.f, dot, c.w);
}

// pack xyz (n,3) -> float4 {x,y,z,|p|^2} (contract-off to match reference)
__global__ void pack_kernel(const float* __restrict__ xyz, float4* __restrict__ out, int n){
  int i = blockIdx.x*blockDim.x + threadIdx.x;
  if (i >= n) return;
  float x = xyz[3*i], y = xyz[3*i+1], z = xyz[3*i+2];
  float sq;
  {
#pragma clang fp contract(off)
    sq = (x*x + y*y) + z*z;
  }
  out[i] = make_float4(x,y,z,sq);
}

// atomtypes (n,6) -> 2-layer MLP -> out (n,6)
__global__ void tt_kernel(const float* __restrict__ at_in,
                          const float* __restrict__ w1, const float* __restrict__ b1,
                          const float* __restrict__ w2, const float* __restrict__ b2,
                          float* __restrict__ out, int n){
  int i = blockIdx.x*blockDim.x + threadIdx.x;
  if (i >= n) return;
  float x[D], h[D];
  #pragma unroll
  for (int j=0;j<D;j++) x[j] = at_in[i*D+j];
  #pragma unroll
  for (int o=0;o<D;o++){
    float acc = b1[o];
    #pragma unroll
    for (int j=0;j<D;j++) acc += w1[o*D+j]*x[j];
    h[o] = lrelu(acc);
  }
  #pragma unroll
  for (int o=0;o<D;o++){
    float acc = b2[o];
    #pragma unroll
    for (int j=0;j<D;j++) acc += w2[o*D+j]*h[j];
    out[i*D+o] = acc;
  }
}

// two independent ascending value-sorts across 64 lanes (ILP-paired)
__device__ __forceinline__ void sort64f2(float& a, float& b, int lane){
  #pragma unroll
  for (int k = 2; k <= 64; k <<= 1){
    #pragma unroll
    for (int j = k >> 1; j >= 1; j >>= 1){
      float oa = __shfl_xor(a, j);
      float ob = __shfl_xor(b, j);
      bool dir = ((lane & j) == 0) == ((lane & k) == 0);
      float na = dir ? fminf(a, oa) : fmaxf(a, oa);
      float nb = dir ? fminf(b, ob) : fmaxf(b, ob);
      a = na; b = nb;
    }
  }
}

// ascending lexicographic (d, i) bitonic sort across 64 lanes
__device__ __forceinline__ void sort64pair(float& d, int& i, int lane){
  #pragma unroll
  for (int k = 2; k <= 64; k <<= 1){
    #pragma unroll
    for (int j = k >> 1; j >= 1; j >>= 1){
      float od = __shfl_xor(d, j);
      int   oi = __shfl_xor(i, j);
      bool lower = (lane & j) == 0;
      bool asc   = (lane & k) == 0;
      bool oless = (od < d) || (od == d && oi < i);
      bool take  = (lower == asc) ? oless : !oless;
      d = take ? od : d;
      i = take ? oi : i;
    }
  }
}

// KNN v3: block = 256 thr = 4 waves = 32 queries x 8 candidate ranges.
// Candidates staged in LDS tiles (coalesced), scanned via broadcast ds_read.
// Pass 1: chunk-mins (8 per (q,range)) in e-space. Threshold: T(q) = KSEL-th
// smallest of q's 64 chunk-mins (disjoint chunks => >=KSEL distinct cands <= T)
// + MARGIN for e-vs-exact rounding. Pass 2: survivor indices into private LDS
// slots. Phase 4: exact lex re-sort (reference formula) across 64 lanes.
template<int KSEL, int OUT_OFF>
__global__ __launch_bounds__(256)
void knn3_kernel(const float4* __restrict__ cand, int ncand,
                 const float4* __restrict__ qarr, int nq,
                 int* __restrict__ oidx, float* __restrict__ odist){
  __shared__ float4 tile[NRG][CHUNK];       // 16 KB
  __shared__ float  cm[QB][NRG*NCH + 1];    // 8.3 KB (pad 65 -> conflict-free)
  __shared__ float  Tq[QB];
  __shared__ float4 qs[QB];
  __shared__ int    slots[QB][NRG][SW];     // 24.6 KB
  __shared__ int    cnts[QB][NRG];

  const int tid  = threadIdx.x;
  const int w    = tid >> 6;
  const int lane = tid & 63;
  const int ql   = lane & (QB-1);           // query lane (0..31)
  const int rho  = w*2 + (lane >> 5);       // range (0..7)
  const int rbase = rho*RNG;

  if (tid < QB){
    int qq = blockIdx.x*QB + tid; if (qq >= nq) qq = nq-1;
    qs[tid] = qarr[qq];
  }
  __syncthreads();
  const float4 qp = qs[ql];

  // ---------------- pass 1: chunk minima ----------------
  for (int c = 0; c < NCH; ++c){
    // stage chunk c of this range: 32 lanes x 4 cands, coalesced
    #pragma unroll
    for (int u = 0; u < 4; ++u){
      int sl = c*CHUNK + ql + 32*u;         // slot in padded range
      bool real = sl < RNG;
      float4 cv = cand[rbase + (real ? sl : 0)];
      if (!real) cv.w = 1e30f;              // sentinel: never a min/survivor
      tile[rho][ql + 32*u] = cv;
    }
    __syncthreads();
    float m0=1e30f, m1=1e30f, m2=1e30f, m3=1e30f;
    #pragma unroll
    for (int i = 0; i < CHUNK; i += 4){
      m0 = fminf(m0, escore(qp, tile[rho][i+0]));
      m1 = fminf(m1, escore(qp, tile[rho][i+1]));
      m2 = fminf(m2, escore(qp, tile[rho][i+2]));
      m3 = fminf(m3, escore(qp, tile[rho][i+3]));
    }
    cm[ql][rho*NCH + c] = fminf(fminf(m0,m1), fminf(m2,m3));
    __syncthreads();
  }

  // ---------------- threshold: KSEL-th smallest of 64 chunk-mins ----------
  #pragma unroll
  for (int u = 0; u < 4; ++u){
    int qa = w*8 + 2*u, qb = qa + 1;
    float a = cm[qa][lane];
    float b = cm[qb][lane];
    sort64f2(a, b, lane);
    if (lane == KSEL-1){ Tq[qa] = a + MARGIN; Tq[qb] = b + MARGIN; }
  }
  __syncthreads();

  // ---------------- pass 2: collect survivors ----------------
  const float Tmy = Tq[ql];
  int cnt = 0;
  for (int c = 0; c < NCH; ++c){
    #pragma unroll
    for (int u = 0; u < 4; ++u){
      int sl = c*CHUNK + ql + 32*u;
      bool real = sl < RNG;
      float4 cv = cand[rbase + (real ? sl : 0)];
      if (!real) cv.w = 1e30f;
      tile[rho][ql + 32*u] = cv;
    }
    __syncthreads();
    #pragma unroll
    for (int i = 0; i < CHUNK; ++i){
      float e = escore(qp, tile[rho][i]);
      if (e <= Tmy){
        if (cnt < SW) slots[ql][rho][cnt] = rbase + c*CHUNK + i;
        cnt++;
      }
    }
    __syncthreads();
  }
  cnts[ql][rho] = cnt;                      // raw count (may exceed SW)
  __syncthreads();

  // ---------------- phase 4: exact select per query ----------------
  for (int u = 0; u < 8; ++u){
    const int qq = w*8 + u;
    const int qgq = blockIdx.x*QB + qq;
    if (qgq >= nq) continue;                // wave-uniform
    int cu[NRG]; int Ctot = 0; bool ovf = false;
    #pragma unroll
    for (int r = 0; r < NRG; ++r){
      int cc = cnts[qq][r];
      if (cc > SW){ ovf = true; cc = SW; }
      cu[r] = cc; Ctot += cc;
    }
    const float4 qv = qs[qq];

    if (!ovf && Ctot <= 64){
      int rem = lane, sel = -1, loc = 0;
      #pragma unroll
      for (int r = 0; r < NRG; ++r){
        bool here = (sel < 0) && (rem < cu[r]);
        if (here){ sel = r; loc = rem; }
        if (sel < 0) rem -= cu[r];
      }
      int g = INT_MAX; float d2 = FLT_MAX;
      if (sel >= 0){
        g = slots[qq][sel][loc];
        float4 cp = cand[g];
        {
#pragma clang fp contract(off)
          float dot = qv.x*cp.x + qv.y*cp.y + qv.z*cp.z;
          d2 = (qv.w + cp.w) - 2.0f*dot;
        }
      }
      sort64pair(d2, g, lane);
      if (lane >= OUT_OFF && lane < OUT_OFF + KOUT){
        float4 cp = cand[g];
        float dist;
        {
#pragma clang fp contract(off)
          float dx=qv.x-cp.x, dy=qv.y-cp.y, dz=qv.z-cp.z;
          dist = (dx*dx + dy*dy) + dz*dz;
        }
        oidx[(size_t)qgq*KOUT + (lane-OUT_OFF)] = g;
        odist[(size_t)qgq*KOUT + (lane-OUT_OFF)] = dist;
      }
    } else if (lane == 0){
      // rare fallback: serial exact top-KSEL (full scan if slot overflow)
      float bd[KSEL]; int bi[KSEL];
      #pragma unroll
      for (int t=0;t<KSEL;t++){ bd[t]=FLT_MAX; bi[t]=INT_MAX; }
      float cmd = FLT_MAX; int cmi = INT_MAX;
      const int nit = ovf ? ncand : NRG*SW;
      for (int e0 = 0; e0 < nit; ++e0){
        int j;
        if (ovf) j = e0;
        else {
          int r = e0 / SW, o = e0 % SW;
          if (o >= cu[r]) continue;
          j = slots[qq][r][o];
        }
        float4 cp = cand[j];
        float d2;
        {
#pragma clang fp contract(off)
          float dot = qv.x*cp.x + qv.y*cp.y + qv.z*cp.z;
          d2 = (qv.w + cp.w) - 2.0f*dot;
        }
        if (d2 < cmd || (d2 == cmd && j < cmi)){
          int rt = 0; float rmd=-FLT_MAX; int rmi=-1;
          for (int t=0;t<KSEL;t++){
            if (bd[t] > rmd || (bd[t]==rmd && bi[t]>rmi)){ rmd=bd[t]; rmi=bi[t]; rt=t; }
          }
          bd[rt]=d2; bi[rt]=j;
          cmd=-FLT_MAX; cmi=-1;
          for (int t=0;t<KSEL;t++){
            if (bd[t] > cmd || (bd[t]==cmd && bi[t]>cmi)){ cmd=bd[t]; cmi=bi[t]; }
          }
        }
      }
      for (int t=0;t<KSEL;t++){
        int rt=-1; float mnd=FLT_MAX; int mni=INT_MAX;
        for (int u2=0;u2<KSEL;u2++){
          if (bd[u2] < mnd || (bd[u2]==mnd && bi[u2]<mni)){ mnd=bd[u2]; mni=bi[u2]; rt=u2; }
        }
        bd[rt]=FLT_MAX; bi[rt]=INT_MAX;
        if (t >= OUT_OFF){
          float4 cp = cand[mni];
          float dist;
          {
#pragma clang fp contract(off)
            float dx=qv.x-cp.x, dy=qv.y-cp.y, dz=qv.z-cp.z;
            dist = (dx*dx + dy*dy) + dz*dz;
          }
          oidx[(size_t)qgq*KOUT + (t-OUT_OFF)] = mni;
          odist[(size_t)qgq*KOUT + (t-OUT_OFF)] = dist;
        }
      }
    }
  }
}

// One message-passing block: out = self + lrelu(groupnorm(sum_k MLP(feat_k)))
// 4 threads per point: each handles 4 of the 16 neighbors, shfl-reduce.
template<bool SELF_ONES>
__global__ __launch_bounds__(256)
void mp_kernel(const float* __restrict__ self_feat,
               const float* __restrict__ nb_src,
               const int* __restrict__ idx,
               const float* __restrict__ dists,
               const float* __restrict__ w1g, const float* __restrict__ b1g,
               const float* __restrict__ w2g, const float* __restrict__ b2g,
               const float* __restrict__ gam, const float* __restrict__ bet,
               float* __restrict__ out, int n){
  __shared__ float w1[H*H], b1v[H], w2[D*H], b2v[D], gm[D], bt[D];
  for (int t=threadIdx.x; t<H*H; t+=blockDim.x) w1[t]=w1g[t];
  if (threadIdx.x < H) b1v[threadIdx.x]=b1g[threadIdx.x];
  for (int t=threadIdx.x; t<D*H; t+=blockDim.x) w2[t]=w2g[t];
  if (threadIdx.x < D){
    b2v[threadIdx.x]=b2g[threadIdx.x];
    gm[threadIdx.x]=gam[threadIdx.x];
    bt[threadIdx.x]=bet[threadIdx.x];
  }
  __syncthreads();
  int tt = blockIdx.x*blockDim.x + threadIdx.x;
  int p = tt >> 2, sub = tt & 3;
  if (p >= n) return;

  float s[D];
  #pragma unroll
  for (int j=0;j<D;j++) s[j] = SELF_ONES ? 1.0f : self_feat[p*D+j];
  float msg[D] = {0,0,0,0,0,0};

  #pragma unroll
  for (int u=0;u<KOUT/4;u++){
    int k = u*4 + sub;
    int j = idx[p*KOUT+k];
    float dd = dists[p*KOUT+k];
    float f[H];
    #pragma unroll
    for (int c=0;c<D;c++) f[c]=s[c];
    #pragma unroll
    for (int c=0;c<D;c++) f[D+c]=nb_src[j*D+c];
    f[2*D]=dd;
    float h[H];
    #pragma unroll
    for (int o=0;o<H;o++){
      float acc=b1v[o];
      #pragma unroll
      for (int c=0;c<H;c++) acc += w1[o*H+c]*f[c];
      h[o]=lrelu(acc);
    }
    #pragma unroll
    for (int o=0;o<D;o++){
      float acc=b2v[o];
      #pragma unroll
      for (int c=0;c<H;c++) acc += w2[o*H+c]*h[c];
      msg[o]+=acc;
    }
  }

  #pragma unroll
  for (int c=0;c<D;c++){
    msg[c] += __shfl_xor(msg[c], 1);
    msg[c] += __shfl_xor(msg[c], 2);
  }

  if (sub == 0){
    float y[D];
    #pragma unroll
    for (int gi=0; gi<2; gi++){
      float m0=msg[gi*3+0], m1=msg[gi*3+1], m2=msg[gi*3+2];
      float mu = ((m0+m1)+m2) / 3.0f;
      float d0=m0-mu, d1=m1-mu, d2v=m2-mu;
      float var = ((d0*d0 + d1*d1) + d2v*d2v) / 3.0f;
      float inv = 1.0f / sqrtf(var + GEPS);
      y[gi*3+0] = d0*inv;
      y[gi*3+1] = d1*inv;
      y[gi*3+2] = d2v*inv;
    }
    #pragma unroll
    for (int c=0;c<D;c++){
      float vv = y[c]*gm[c] + bt[c];
      out[p*D+c] = s[c] + lrelu(vv);
    }
  }
}

extern "C" void kernel_launch(void* const* d_in, const int* in_sizes, int n_in,
                              void* d_out, int out_size, void* d_ws, size_t ws_size,
                              hipStream_t stream){
  const float* xyz       = (const float*)d_in[0];
  const float* atom_xyz  = (const float*)d_in[1];
  const float* atomtypes = (const float*)d_in[2];
  const float* tt_w1 = (const float*)d_in[5];
  const float* tt_b1 = (const float*)d_in[6];
  const float* tt_w2 = (const float*)d_in[7];
  const float* tt_b2 = (const float*)d_in[8];
  const float* aa_w1 = (const float*)d_in[9];
  const float* aa_b1 = (const float*)d_in[10];
  const float* aa_w2 = (const float*)d_in[11];
  const float* aa_b2 = (const float*)d_in[12];
  const float* aa_gamma = (const float*)d_in[13];
  const float* aa_beta  = (const float*)d_in[14];
  const float* em_w1 = (const float*)d_in[15];
  const float* em_b1 = (const float*)d_in[16];
  const float* em_w2 = (const float*)d_in[17];
  const float* em_b2 = (const float*)d_in[18];
  const float* em_gamma = (const float*)d_in[19];
  const float* em_beta  = (const float*)d_in[20];

  const int n_pts = in_sizes[0]/3;
  const int n_at  = in_sizes[1]/3;

  char* ws = (char*)d_ws;
  float4* atomsP = (float4*)ws; ws += (size_t)n_at*sizeof(float4);
  float4* ptsP   = (float4*)ws; ws += (size_t)n_pts*sizeof(float4);
  float* fa   = (float*)ws; ws += (size_t)n_at*D*4;
  float* fb   = (float*)ws; ws += (size_t)n_at*D*4;
  int*   idxA = (int*)ws;   ws += (size_t)n_at*KOUT*4;
  float* distA= (float*)ws; ws += (size_t)n_at*KOUT*4;
  int*   idxP = (int*)ws;   ws += (size_t)n_pts*KOUT*4;
  float* distP= (float*)ws; ws += (size_t)n_pts*KOUT*4;
  float* ea   = (float*)ws; ws += (size_t)n_pts*D*4;
  float* eb   = (float*)ws; ws += (size_t)n_pts*D*4;
  float* outf = (float*)d_out;

  pack_kernel<<<(n_at +255)/256,256,0,stream>>>(atom_xyz, atomsP, n_at);
  pack_kernel<<<(n_pts+255)/256,256,0,stream>>>(xyz, ptsP, n_pts);

  tt_kernel<<<(n_at+255)/256,256,0,stream>>>(atomtypes, tt_w1,tt_b1,tt_w2,tt_b2, fa, n_at);

  knn3_kernel<17,1><<<(n_at +QB-1)/QB,256,0,stream>>>(atomsP, n_at, atomsP, n_at, idxA, distA);

  mp_kernel<false><<<(n_at*4+255)/256,256,0,stream>>>(fa, fa, idxA, distA,
      aa_w1+0*H*H, aa_b1+0*H, aa_w2+0*D*H, aa_b2+0*D, aa_gamma+0*D, aa_beta+0*D, fb, n_at);
  mp_kernel<false><<<(n_at*4+255)/256,256,0,stream>>>(fb, fb, idxA, distA,
      aa_w1+1*H*H, aa_b1+1*H, aa_w2+1*D*H, aa_b2+1*D, aa_gamma+1*D, aa_beta+1*D, fa, n_at);
  mp_kernel<false><<<(n_at*4+255)/256,256,0,stream>>>(fa, fa, idxA, distA,
      aa_w1+2*H*H, aa_b1+2*H, aa_w2+2*D*H, aa_b2+2*D, aa_gamma+2*D, aa_beta+2*D, fb, n_at);
  // final atom features in fb

  knn3_kernel<16,0><<<(n_pts+QB-1)/QB,256,0,stream>>>(atomsP, n_at, ptsP, n_pts, idxP, distP);

  mp_kernel<true ><<<(n_pts*4+255)/256,256,0,stream>>>(nullptr, fb, idxP, distP,
      em_w1+0*H*H, em_b1+0*H, em_w2+0*D*H, em_b2+0*D, em_gamma+0*D, em_beta+0*D, ea, n_pts);
  mp_kernel<false><<<(n_pts*4+255)/256,256,0,stream>>>(ea, fb, idxP, distP,
      em_w1+1*H*H, em_b1+1*H, em_w2+1*D*H, em_b2+1*D, em_gamma+1*D, em_beta+1*D, eb, n_pts);
  mp_kernel<false><<<(n_pts*4+255)/256,256,0,stream>>>(eb, fb, idxP, distP,
      em_w1+2*H*H, em_b1+2*H, em_w2+2*D*H, em_b2+2*D, em_gamma+2*D, em_beta+2*D, outf, n_pts);
}